// Round 2
// baseline (21841.899 us; speedup 1.0000x reference)
//
#include <hip/hip_runtime.h>
#include <hip/hip_bf16.h>

#define NB 16
#define SB 2048
#define DB 256
#define EB 512
#define LB 4
#define NSEG_CAP 1024
#define GRID_MAIN 128

typedef __bf16 bf16x8 __attribute__((ext_vector_type(8)));
typedef float  f32x4  __attribute__((ext_vector_type(4)));

// ---------------- workspace layout (bytes) ----------------
#define OFF_XBF   0ull
#define SZ_XBF    (16ull*2048*256*2)          // x as bf16
#define OFF_W     (OFF_XBF + SZ_XBF)          // uniform [l][2048][1024] bf16
#define SZ_W      (4ull*2048*1024*2)
#define OFF_BIAS  (OFF_W + SZ_W)              // 4*2048 f32 (b_ih+b_hh)
#define OFF_H     (OFF_BIAS + 4ull*2048*4)    // [l][parity][seg][e] bf16
#define SZ_H      (4ull*2*NSEG_CAP*EB*2)
#define OFF_C     (OFF_H + SZ_H)              // [l][seg][e] f32
#define SZ_C      (4ull*NSEG_CAP*EB*4)
#define OFF_SROW   (OFF_C + SZ_C)
#define OFF_SSTART (OFF_SROW  + 4ull*NSEG_CAP)
#define OFF_SLEN   (OFF_SSTART + 4ull*NSEG_CAP)
#define OFF_SSLOT  (OFF_SLEN  + 4ull*NSEG_CAP)
#define OFF_ACT   (OFF_SSLOT + 4ull*NSEG_CAP) // active[r], 2048 ints
#define OFF_META  (OFF_ACT + 4ull*2048)       // [0]=NSEG [1]=maxlen
#define OFF_FLAGS (OFF_META + 256ull)         // [l][r][32] u32
#define SZ_FLAGS  (4ull*2048*32*4)

__device__ __forceinline__ unsigned short f2bf(float f) {
  union { float f; unsigned u; } v; v.f = f;
  unsigned r = v.u + 0x7FFFu + ((v.u >> 16) & 1u);
  return (unsigned short)(r >> 16);
}
__device__ __forceinline__ float sigf(float x) {
  x = fminf(30.f, fmaxf(-30.f, x));
  return 1.f / (1.f + __expf(-x));
}
__device__ __forceinline__ float tanhx(float x) {
  x = fminf(15.f, fmaxf(-15.f, x));
  float e = __expf(-2.f * x);
  return (1.f - e) / (1.f + e);
}

// ---------------- kernel 1: conversions + zeroing ----------------
__global__ void k_conv(const float* __restrict__ x, const float* __restrict__ wih0,
                       const float* __restrict__ wihr, const float* __restrict__ whh,
                       const float* __restrict__ bih, const float* __restrict__ bhh,
                       float* __restrict__ dout, int out_size, char* __restrict__ ws) {
  long long gid = (long long)blockIdx.x * blockDim.x + threadIdx.x;
  long long stride = (long long)gridDim.x * blockDim.x;
  // zero output
  for (long long i = gid; i < out_size; i += stride) dout[i] = 0.f;
  // zero h + c (contiguous region)
  unsigned* hz = (unsigned*)(ws + OFF_H);
  long long hcw = (long long)(SZ_H + SZ_C) / 4;
  for (long long i = gid; i < hcw; i += stride) hz[i] = 0u;
  // zero flags
  unsigned* fz = (unsigned*)(ws + OFF_FLAGS);
  for (long long i = gid; i < (long long)(SZ_FLAGS / 4); i += stride) fz[i] = 0u;
  // bias sum
  float* bias = (float*)(ws + OFF_BIAS);
  for (long long i = gid; i < 4 * 2048; i += stride) bias[i] = bih[i] + bhh[i];
  // uniform weights [l][2048 n][1024 k] bf16
  unsigned short* wbf = (unsigned short*)(ws + OFF_W);
  for (long long i = gid; i < 4ll * 2048 * 1024; i += stride) {
    int l = (int)(i >> 21);
    int rem = (int)(i & ((1 << 21) - 1));
    int n = rem >> 10, k = rem & 1023;
    float v;
    if (l == 0)
      v = (k < 256) ? wih0[n * 256 + k]
        : (k < 512) ? 0.f
        : whh[(long long)n * 512 + (k - 512)];
    else
      v = (k < 512) ? wihr[((long long)(l - 1) * 2048 + n) * 512 + k]
                    : whh[((long long)l * 2048 + n) * 512 + (k - 512)];
    wbf[i] = f2bf(v);
  }
  // x -> bf16
  unsigned short* xb = (unsigned short*)(ws + OFF_XBF);
  for (long long i = gid; i < (long long)NB * SB * DB; i += stride) xb[i] = f2bf(x[i]);
}

// ---------------- kernel 2: segmentation + sort (1 block) ----------------
__global__ void k_seg(const void* __restrict__ maskp, char* __restrict__ ws,
                      float* __restrict__ dout, int Sp) {
  __shared__ unsigned bits[NB][64];
  __shared__ int hist[2050];
  __shared__ int sufx[2051];
  __shared__ int part[256];
  __shared__ unsigned metapk[NSEG_CAP];
  __shared__ int slotar[NSEG_CAP];
  __shared__ int rowcnt[NB];
  __shared__ int flagbits, nseg, maxlen;
  int tid = threadIdx.x;
  if (tid == 0) { flagbits = 0; nseg = 0; maxlen = 0; }
  for (int i = tid; i < 2050; i += 256) hist[i] = 0;
  __syncthreads();
  // ---- detect mask storage: u8 / i32 / f32 / 64-bit ----
  const unsigned* mw = (const unsigned*)maskp;
  int fb = 0;
  for (int i = tid; i < 8192; i += 256) {
    unsigned w = mw[i];
    if (w == 0x3F800000u) fb |= 2;
    if (w == 0x3FF00000u) fb |= 4;
    if (w & 0xFFFFFF00u) fb |= 1;
    if ((i & 1) && w) fb |= 8;
  }
  if (fb) atomicOr(&flagbits, fb);
  __syncthreads();
  int f = flagbits;
  int kind = (f & 4) ? 3 : (f & 2) ? 2 : (f & 1) ? 0 : (f & 8) ? 1 : 3;
  // ---- pack separator bits ----
  for (int w = tid; w < NB * 64; w += 256) {
    int row = w >> 6, j = w & 63;
    unsigned b = 0;
    int t0 = j * 32;
    for (int z = 0; z < 32; ++z) {
      long long idx = (long long)row * SB + t0 + z;
      bool sep;
      if (kind == 0)      sep = ((const unsigned char*)maskp)[idx] != 0;
      else if (kind == 1) sep = ((const int*)maskp)[idx] != 0;
      else if (kind == 2) sep = ((const float*)maskp)[idx] != 0.f;
      else                sep = ((const unsigned long long*)maskp)[idx] != 0ull;
      b |= (sep ? 1u : 0u) << z;
    }
    bits[row][j] = b;
  }
  __syncthreads();
  // ---- per-row segment extraction ----
  if (tid < NB) {
    int row = tid, i = 0, cnt = 0;
    for (int w = 0; w < 64; ++w) {
      unsigned b = bits[row][w];
      while (b) {
        int z = __ffs(b) - 1; b &= b - 1;
        int t = w * 32 + z;
        if (i != t) {
          int len = t - i;
          int idx = atomicAdd(&nseg, 1);
          if (idx < NSEG_CAP) { metapk[idx] = ((unsigned)row << 23) | ((unsigned)i << 12) | (unsigned)len; slotar[idx] = cnt; }
          atomicAdd(&hist[len], 1); atomicMax(&maxlen, len);
          cnt++;
        }
        i = t + 1;
      }
    }
    if (i != SB) {
      int len = SB - i;
      int idx = atomicAdd(&nseg, 1);
      if (idx < NSEG_CAP) { metapk[idx] = ((unsigned)row << 23) | ((unsigned)i << 12) | (unsigned)len; slotar[idx] = cnt; }
      atomicAdd(&hist[len], 1); atomicMax(&maxlen, len);
      cnt++;
    }
    rowcnt[row] = cnt;
  }
  __syncthreads();
  // ---- suffix sums: sufx[k] = #segs with len >= k ----
  {
    int lo = tid * 9, hi = lo + 9; if (hi > 2050) hi = 2050;
    int s = 0;
    for (int k = lo; k < hi; ++k) s += hist[k];
    part[tid] = s;
  }
  __syncthreads();
  {
    int tail = 0;
    for (int t2 = tid + 1; t2 < 256; ++t2) tail += part[t2];
    int lo = tid * 9, hi = lo + 9; if (hi > 2050) hi = 2050;
    int run = tail;
    for (int k = hi - 1; k >= lo; --k) { run += hist[k]; sufx[k] = run; }
  }
  __syncthreads();
  int* act = (int*)(ws + OFF_ACT);
  for (int r = tid; r < 2048; r += 256) act[r] = sufx[r + 1];
  for (int i = tid; i < 2050; i += 256) hist[i] = 0;
  __syncthreads();
  int NSEG = nseg < NSEG_CAP ? nseg : NSEG_CAP;
  int* srow = (int*)(ws + OFF_SROW);
  int* sstart = (int*)(ws + OFF_SSTART);
  int* slen = (int*)(ws + OFF_SLEN);
  int* sslot = (int*)(ws + OFF_SSLOT);
  for (int i = tid; i < NSEG; i += 256) {
    unsigned m = metapk[i];
    int len = m & 0xFFF, st = (m >> 12) & 0x7FF, row = (int)(m >> 23);
    int pos = sufx[len + 1] + atomicAdd(&hist[len], 1);
    srow[pos] = row; sstart[pos] = st; slen[pos] = len; sslot[pos] = slotar[i];
  }
  int* meta = (int*)(ws + OFF_META);
  if (tid == 0) { meta[0] = NSEG; meta[1] = maxlen; }
  __syncthreads();
  float* omask = dout + (long long)NB * Sp * EB;
  for (int i = tid; i < NB * Sp; i += 256) {
    int row = i / Sp, slot = i % Sp;
    omask[i] = (slot < rowcnt[row]) ? 0.f : 1.f;
  }
}

// ---------------- kernel 3: persistent dataflow LSTM pipeline ----------------
// block = (layer l, 16 e-values). W rows (4 gates x 16 e x K=1024) live in VGPRs.
__global__ void __launch_bounds__(256, 1)
k_main(char* __restrict__ ws, float* __restrict__ dout, int Sp) {
  __shared__ int act_s[2048];
  __shared__ int meta_s[2];
  __shared__ float glds[4][64][17];   // [gate][m][e], padded
  __shared__ float bias_s[4][16];
  int tid = threadIdx.x;
  const int l = blockIdx.x >> 5;        // layer 0..3
  const int wb = blockIdx.x & 31;       // within-layer block id
  const int e0 = wb << 4;               // 16 e-values per block
  {
    const int* act = (const int*)(ws + OFF_ACT);
    for (int i = tid; i < 2048; i += 256) act_s[i] = act[i];
    if (tid < 2) meta_s[tid] = ((const int*)(ws + OFF_META))[tid];
    if (tid < 64) {
      int g = tid >> 4, e = tid & 15;
      bias_s[g][e] = ((const float*)(ws + OFF_BIAS))[l * 2048 + g * 512 + e0 + e];
    }
  }
  __syncthreads();
  const int maxlen = meta_s[1];
  const int wave = tid >> 6, lane = tid & 63, l15 = lane & 15, lq = lane >> 4;
  const char* wsb = ws;
  // ---- load this wave's W rows into registers (gate = wave) ----
  bf16x8 breg[32];
  {
    unsigned rowoff = ((unsigned)(l * 2048 + wave * 512 + e0 + l15)) << 10; // elem idx
    #pragma unroll
    for (int kk = 0; kk < 32; ++kk)
      breg[kk] = *(const bf16x8*)(wsb + OFF_W + (unsigned long long)(rowoff + kk * 32 + lq * 8) * 2);
  }
  const int* srow  = (const int*)(ws + OFF_SROW);
  const int* sstart = (const int*)(ws + OFF_SSTART);
  const int* slen  = (const int*)(ws + OFF_SLEN);
  const int* sslot = (const int*)(ws + OFF_SSLOT);
  unsigned* flags = (unsigned*)(ws + OFF_FLAGS);

  for (int r = 0; r < maxlen; ++r) {
    // ---- dataflow wait: producer layer, own recurrence, consumer back-pressure ----
    const bool nA = (l > 0), nB = (r > 0), nC = (l < 3 && r >= 2);
    if (wave == 0 && (nA | nB | nC)) {
      int li = lane & 31;
      while (true) {
        unsigned ok = 1;
        if (nA) ok &= (__hip_atomic_load(flags + ((((l - 1) * 2048 + r) << 5) + li),
                                         __ATOMIC_RELAXED, __HIP_MEMORY_SCOPE_AGENT) != 0);
        if (nB) ok &= (__hip_atomic_load(flags + (((l * 2048 + (r - 1)) << 5) + li),
                                         __ATOMIC_RELAXED, __HIP_MEMORY_SCOPE_AGENT) != 0);
        if (nC) ok &= (__hip_atomic_load(flags + ((((l + 1) * 2048 + (r - 2)) << 5) + li),
                                         __ATOMIC_RELAXED, __HIP_MEMORY_SCOPE_AGENT) != 0);
        if (__all((int)ok)) break;
        __builtin_amdgcn_s_sleep(2);
      }
      __threadfence();   // acquire: invalidate L1 before reading peers' h
    }
    __syncthreads();

    const int M = act_s[r];
    const int nmch = (M + 63) >> 6;
    for (int mch = 0; mch < nmch; ++mch) {
      const int segbase = mch << 6;
      int Mv = M - segbase; if (Mv > 64) Mv = 64;
      const int mfmax = (Mv + 15) >> 4;
      // per-lane A row base byte offsets
      unsigned aoff_lo[4], aoff_hi[4];
      #pragma unroll
      for (int mf = 0; mf < 4; ++mf) {
        int m = (mf << 4) + l15;
        int sg = segbase + ((m < Mv) ? m : 0);
        unsigned lo;
        if (l == 0) {
          int rw = srow[sg], st = sstart[sg];
          lo = (unsigned)OFF_XBF + (((unsigned)(rw * SB + st + r)) * DB + 8u * lq) * 2u;
        } else {
          lo = (unsigned)OFF_H + ((((unsigned)((l - 1) * 2 + (r & 1)) * NSEG_CAP) + sg) * EB + 8u * lq) * 2u;
        }
        aoff_lo[mf] = lo;
        aoff_hi[mf] = (unsigned)OFF_H + ((((unsigned)(l * 2 + ((r - 1) & 1)) * NSEG_CAP) + sg) * EB + 8u * lq) * 2u;
      }
      f32x4 acc[4];
      #pragma unroll
      for (int mf = 0; mf < 4; ++mf) acc[mf] = (f32x4){0.f, 0.f, 0.f, 0.f};
      #pragma unroll
      for (int kk = 0; kk < 32; ++kk) {
        if (kk >= 8 && kk < 16) { if (l == 0) continue; }   // layer0: zero pad region
        const int k0 = kk << 5;
        const bool lopart = (k0 < 512);
        #pragma unroll
        for (int mf = 0; mf < 4; ++mf) {
          if (mf < mfmax) {
            unsigned off = lopart ? (aoff_lo[mf] + (unsigned)k0 * 2u)
                                  : (aoff_hi[mf] + (unsigned)(k0 - 512) * 2u);
            bf16x8 a = *(const bf16x8*)(wsb + off);
            acc[mf] = __builtin_amdgcn_mfma_f32_16x16x32_bf16(a, breg[kk], acc[mf], 0, 0, 0);
          }
        }
      }
      // ---- gate exchange via LDS ----
      #pragma unroll
      for (int mf = 0; mf < 4; ++mf) {
        if (mf < mfmax) {
          #pragma unroll
          for (int reg = 0; reg < 4; ++reg)
            glds[wave][(mf << 4) + (lq << 2) + reg][l15] = acc[mf][reg];
        }
      }
      __syncthreads();
      // ---- epilogue: 1024 (m,e) cells over 256 threads ----
      #pragma unroll
      for (int q = 0; q < 4; ++q) {
        int cell = tid + (q << 8);
        int m = cell >> 4, e = cell & 15;
        if (m < Mv) {
          int sg = segbase + m;
          float gi = glds[0][m][e] + bias_s[0][e];
          float gf = glds[1][m][e] + bias_s[1][e];
          float gg = glds[2][m][e] + bias_s[2][e];
          float go = glds[3][m][e] + bias_s[3][e];
          float* cptr = (float*)(ws + OFF_C + (((unsigned)(l * NSEG_CAP + sg) * EB + e0 + e) * 4u));
          float cold = *cptr;
          float cnew = sigf(gf) * cold + sigf(gi) * tanhx(gg);
          float hnew = sigf(go) * tanhx(cnew);
          *cptr = cnew;
          *(unsigned short*)(ws + OFF_H + (((unsigned)((l * 2 + (r & 1)) * NSEG_CAP + sg) * EB + e0 + e) * 2u)) = f2bf(hnew);
          if (l == 3) {
            if (r == slen[sg] - 1) {
              int rw = srow[sg], sl = sslot[sg];
              if (sl < Sp) dout[(((long long)rw * Sp + sl) << 9) + e0 + e] = hnew;
            }
          }
        }
      }
      __syncthreads();
    }
    // ---- arrive: one release store, no RMW ----
    if (tid == 0) {
      __threadfence();
      __hip_atomic_store(flags + (((l * 2048 + r) << 5) + wb), 1u,
                         __ATOMIC_RELEASE, __HIP_MEMORY_SCOPE_AGENT);
    }
  }
}

extern "C" void kernel_launch(void* const* d_in, const int* in_sizes, int n_in,
                              void* d_out, int out_size, void* d_ws, size_t ws_size,
                              hipStream_t stream) {
  const float* x    = (const float*)d_in[0];
  const void*  mask = d_in[1];
  const float* wih0 = (const float*)d_in[2];
  const float* wihr = (const float*)d_in[3];
  const float* whh  = (const float*)d_in[4];
  const float* bih  = (const float*)d_in[5];
  const float* bhh  = (const float*)d_in[6];
  float* out = (float*)d_out;
  char* ws = (char*)d_ws;
  int Sp = out_size / (NB * (EB + 1));   // out = N*Sp*E  +  N*Sp mask

  k_conv<<<dim3(2048), dim3(256), 0, stream>>>(x, wih0, wihr, whh, bih, bhh, out, out_size, ws);
  k_seg<<<dim3(1), dim3(256), 0, stream>>>(mask, ws, out, Sp);
  k_main<<<dim3(GRID_MAIN), dim3(256), 0, stream>>>(ws, out, Sp);
}

// Round 3
// 7539.928 us; speedup vs baseline: 2.8968x; 2.8968x over previous
//
#include <hip/hip_runtime.h>
#include <hip/hip_bf16.h>

#define NB 16
#define SB 2048
#define DB 256
#define EB 512
#define LB 4
#define NPAR 4
#define NSEG_CAP 1024
#define GRID_MAIN 128

typedef __bf16 bf16x8 __attribute__((ext_vector_type(8)));
typedef float  f32x4  __attribute__((ext_vector_type(4)));
typedef float  f32x16 __attribute__((ext_vector_type(16)));

// ---------------- workspace layout (bytes) ----------------
#define OFF_XBF   0ull
#define SZ_XBF    (16ull*2048*256*2)          // x as bf16
#define OFF_W     (OFF_XBF + SZ_XBF)          // uniform [l][2048][1024] bf16
#define SZ_W      (4ull*2048*1024*2)
#define OFF_BIAS  (OFF_W + SZ_W)              // 4*2048 f32 (b_ih+b_hh)
#define OFF_H     (OFF_BIAS + 4ull*2048*4)    // [l][par(4)][seg][e] bf16
#define SZ_H      (4ull*NPAR*NSEG_CAP*EB*2)
#define OFF_C     (OFF_H + SZ_H)              // [l][seg][e] f32
#define SZ_C      (4ull*NSEG_CAP*EB*4)
#define OFF_SROW   (OFF_C + SZ_C)
#define OFF_SSTART (OFF_SROW  + 4ull*NSEG_CAP)
#define OFF_SLEN   (OFF_SSTART + 4ull*NSEG_CAP)
#define OFF_SSLOT  (OFF_SLEN  + 4ull*NSEG_CAP)
#define OFF_ACT   (OFF_SSLOT + 4ull*NSEG_CAP) // active[r], 2048 ints
#define OFF_META  (OFF_ACT + 4ull*2048)       // [0]=NSEG [1]=maxlen
#define OFF_FLAGS (OFF_META + 256ull)         // [l][r][32] u32
#define SZ_FLAGS  (4ull*2048*32*4)

__device__ __forceinline__ unsigned short f2bf(float f) {
  union { float f; unsigned u; } v; v.f = f;
  unsigned r = v.u + 0x7FFFu + ((v.u >> 16) & 1u);
  return (unsigned short)(r >> 16);
}
__device__ __forceinline__ float sigf(float x) {
  x = fminf(30.f, fmaxf(-30.f, x));
  return 1.f / (1.f + __expf(-x));
}
__device__ __forceinline__ float tanhx(float x) {
  x = fminf(15.f, fmaxf(-15.f, x));
  float e = __expf(-2.f * x);
  return (1.f - e) / (1.f + e);
}

// ---------------- kernel 1: conversions + zeroing ----------------
__global__ void k_conv(const float* __restrict__ x, const float* __restrict__ wih0,
                       const float* __restrict__ wihr, const float* __restrict__ whh,
                       const float* __restrict__ bih, const float* __restrict__ bhh,
                       float* __restrict__ dout, int out_size, char* __restrict__ ws) {
  long long gid = (long long)blockIdx.x * blockDim.x + threadIdx.x;
  long long stride = (long long)gridDim.x * blockDim.x;
  for (long long i = gid; i < out_size; i += stride) dout[i] = 0.f;
  unsigned* hz = (unsigned*)(ws + OFF_H);
  long long hcw = (long long)(SZ_H + SZ_C) / 4;
  for (long long i = gid; i < hcw; i += stride) hz[i] = 0u;
  unsigned* fz = (unsigned*)(ws + OFF_FLAGS);
  for (long long i = gid; i < (long long)(SZ_FLAGS / 4); i += stride) fz[i] = 0u;
  float* bias = (float*)(ws + OFF_BIAS);
  for (long long i = gid; i < 4 * 2048; i += stride) bias[i] = bih[i] + bhh[i];
  // uniform weights [l][2048 n][1024 k] bf16; l==0: k<256 = W_ih0, 256..511 = 0, 512+ = W_hh[0]
  unsigned short* wbf = (unsigned short*)(ws + OFF_W);
  for (long long i = gid; i < 4ll * 2048 * 1024; i += stride) {
    int l = (int)(i >> 21);
    int rem = (int)(i & ((1 << 21) - 1));
    int n = rem >> 10, k = rem & 1023;
    float v;
    if (l == 0)
      v = (k < 256) ? wih0[n * 256 + k]
        : (k < 512) ? 0.f
        : whh[(long long)n * 512 + (k - 512)];
    else
      v = (k < 512) ? wihr[((long long)(l - 1) * 2048 + n) * 512 + k]
                    : whh[((long long)l * 2048 + n) * 512 + (k - 512)];
    wbf[i] = f2bf(v);
  }
  unsigned short* xb = (unsigned short*)(ws + OFF_XBF);
  for (long long i = gid; i < (long long)NB * SB * DB; i += stride) xb[i] = f2bf(x[i]);
}

// ---------------- kernel 2: segmentation + sort (1 block) ----------------
__global__ void k_seg(const void* __restrict__ maskp, char* __restrict__ ws,
                      float* __restrict__ dout, int Sp) {
  __shared__ unsigned bits[NB][64];
  __shared__ int hist[2050];
  __shared__ int sufx[2051];
  __shared__ int part[256];
  __shared__ unsigned metapk[NSEG_CAP];
  __shared__ int slotar[NSEG_CAP];
  __shared__ int rowcnt[NB];
  __shared__ int flagbits, nseg, maxlen;
  int tid = threadIdx.x;
  if (tid == 0) { flagbits = 0; nseg = 0; maxlen = 0; }
  for (int i = tid; i < 2050; i += 256) hist[i] = 0;
  __syncthreads();
  const unsigned* mw = (const unsigned*)maskp;
  int fb = 0;
  for (int i = tid; i < 8192; i += 256) {
    unsigned w = mw[i];
    if (w == 0x3F800000u) fb |= 2;
    if (w == 0x3FF00000u) fb |= 4;
    if (w & 0xFFFFFF00u) fb |= 1;
    if ((i & 1) && w) fb |= 8;
  }
  if (fb) atomicOr(&flagbits, fb);
  __syncthreads();
  int f = flagbits;
  int kind = (f & 4) ? 3 : (f & 2) ? 2 : (f & 1) ? 0 : (f & 8) ? 1 : 3;
  for (int w = tid; w < NB * 64; w += 256) {
    int row = w >> 6, j = w & 63;
    unsigned b = 0;
    int t0 = j * 32;
    for (int z = 0; z < 32; ++z) {
      long long idx = (long long)row * SB + t0 + z;
      bool sep;
      if (kind == 0)      sep = ((const unsigned char*)maskp)[idx] != 0;
      else if (kind == 1) sep = ((const int*)maskp)[idx] != 0;
      else if (kind == 2) sep = ((const float*)maskp)[idx] != 0.f;
      else                sep = ((const unsigned long long*)maskp)[idx] != 0ull;
      b |= (sep ? 1u : 0u) << z;
    }
    bits[row][j] = b;
  }
  __syncthreads();
  if (tid < NB) {
    int row = tid, i = 0, cnt = 0;
    for (int w = 0; w < 64; ++w) {
      unsigned b = bits[row][w];
      while (b) {
        int z = __ffs(b) - 1; b &= b - 1;
        int t = w * 32 + z;
        if (i != t) {
          int len = t - i;
          int idx = atomicAdd(&nseg, 1);
          if (idx < NSEG_CAP) { metapk[idx] = ((unsigned)row << 23) | ((unsigned)i << 12) | (unsigned)len; slotar[idx] = cnt; }
          atomicAdd(&hist[len], 1); atomicMax(&maxlen, len);
          cnt++;
        }
        i = t + 1;
      }
    }
    if (i != SB) {
      int len = SB - i;
      int idx = atomicAdd(&nseg, 1);
      if (idx < NSEG_CAP) { metapk[idx] = ((unsigned)row << 23) | ((unsigned)i << 12) | (unsigned)len; slotar[idx] = cnt; }
      atomicAdd(&hist[len], 1); atomicMax(&maxlen, len);
      cnt++;
    }
    rowcnt[row] = cnt;
  }
  __syncthreads();
  {
    int lo = tid * 9, hi = lo + 9; if (hi > 2050) hi = 2050;
    int s = 0;
    for (int k = lo; k < hi; ++k) s += hist[k];
    part[tid] = s;
  }
  __syncthreads();
  {
    int tail = 0;
    for (int t2 = tid + 1; t2 < 256; ++t2) tail += part[t2];
    int lo = tid * 9, hi = lo + 9; if (hi > 2050) hi = 2050;
    int run = tail;
    for (int k = hi - 1; k >= lo; --k) { run += hist[k]; sufx[k] = run; }
  }
  __syncthreads();
  int* act = (int*)(ws + OFF_ACT);
  for (int r = tid; r < 2048; r += 256) act[r] = sufx[r + 1];
  for (int i = tid; i < 2050; i += 256) hist[i] = 0;
  __syncthreads();
  int NSEG = nseg < NSEG_CAP ? nseg : NSEG_CAP;
  int* srow = (int*)(ws + OFF_SROW);
  int* sstart = (int*)(ws + OFF_SSTART);
  int* slen = (int*)(ws + OFF_SLEN);
  int* sslot = (int*)(ws + OFF_SSLOT);
  for (int i = tid; i < NSEG; i += 256) {
    unsigned m = metapk[i];
    int len = m & 0xFFF, st = (m >> 12) & 0x7FF, row = (int)(m >> 23);
    int pos = sufx[len + 1] + atomicAdd(&hist[len], 1);
    srow[pos] = row; sstart[pos] = st; slen[pos] = len; sslot[pos] = slotar[i];
  }
  int* meta = (int*)(ws + OFF_META);
  if (tid == 0) { meta[0] = NSEG; meta[1] = maxlen; }
  __syncthreads();
  float* omask = dout + (long long)NB * Sp * EB;
  for (int i = tid; i < NB * Sp; i += 256) {
    int row = i / Sp, slot = i % Sp;
    omask[i] = (slot < rowcnt[row]) ? 0.f : 1.f;
  }
}

// ---------------- kernel 3: persistent dataflow LSTM pipeline ----------------
// block = (layer l, 16 e-values) -> 64 W-rows. 8 waves = (rg: row-half, kh: K-half, mh: m-half).
// B (weights) register-stationary: 32 frags x 4 VGPR = 128 VGPR per wave (its K-half).
__global__ void __launch_bounds__(512, 2)
k_main(char* __restrict__ ws, float* __restrict__ dout, int Sp) {
  __shared__ float glds[2][64][65];   // [kh][m][rho] partial-gate exchange
  __shared__ float bias_s[64];
  __shared__ int act_s[2048];
  const int tid = threadIdx.x;
  const int l = blockIdx.x >> 5, wb = blockIdx.x & 31, e0 = wb << 4;
  const int wave = tid >> 6, lane = tid & 63;
  const int mh = wave & 1, kh = (wave >> 1) & 1, rg = wave >> 2;
  const int l31 = lane & 31, lhi = lane >> 5;

  {
    const int* act = (const int*)(ws + OFF_ACT);
    for (int i = tid; i < 2048; i += 512) act_s[i] = act[i];
    if (tid < 64) bias_s[tid] =
        ((const float*)(ws + OFF_BIAS))[l * 2048 + (tid >> 4) * 512 + e0 + (tid & 15)];
  }
  const int maxlen = ((const int*)(ws + OFF_META))[1];
  const char* wsb = ws;

  // ---- load B-frags (this wave's 32 rows x its K-half) into registers ----
  bf16x8 breg[32];
  {
    int rho = rg * 32 + l31;                 // local row 0..63
    int g = rho >> 4, e = rho & 15;
    const char* wrow = wsb + OFF_W + ((size_t)(l * 2048 + g * 512 + e0 + e)) * 2048;
    const int kbase = kh * 512 + lhi * 8;
    #pragma unroll
    for (int t = 0; t < 32; ++t)
      breg[t] = *(const bf16x8*)(wrow + (size_t)(kbase + t * 16) * 2);
  }
  __syncthreads();

  const int* srow  = (const int*)(ws + OFF_SROW);
  const int* sstart = (const int*)(ws + OFF_SSTART);
  const int* slen  = (const int*)(ws + OFF_SLEN);
  const int* sslot = (const int*)(ws + OFF_SSLOT);
  unsigned* flags = (unsigned*)(ws + OFF_FLAGS);
  const bool l0k0 = (l == 0) && (kh == 0);

  for (int r = 0; r < maxlen; ++r) {
    // ---- dataflow wait: producer (l-1,r), recurrence (l,r-1), back-pressure (l+1,r-4) ----
    const bool nA = (l > 0), nB = (r > 0), nC = (l < 3) && (r >= 4);
    if (wave == 0 && (nA | nB | nC)) {
      int li = lane & 31;
      while (true) {
        unsigned ok = 1;
        if (nA) ok &= (__hip_atomic_load(flags + ((((l - 1) * 2048 + r) << 5) + li),
                                         __ATOMIC_RELAXED, __HIP_MEMORY_SCOPE_AGENT) != 0);
        if (nB) ok &= (__hip_atomic_load(flags + (((l * 2048 + (r - 1)) << 5) + li),
                                         __ATOMIC_RELAXED, __HIP_MEMORY_SCOPE_AGENT) != 0);
        if (nC) ok &= (__hip_atomic_load(flags + ((((l + 1) * 2048 + (r - 4)) << 5) + li),
                                         __ATOMIC_RELAXED, __HIP_MEMORY_SCOPE_AGENT) != 0);
        if (__all((int)ok)) break;
        __builtin_amdgcn_s_sleep(2);
      }
      __threadfence();   // acquire
    }
    __syncthreads();

    const int M = act_s[r];
    const int nmch = (M + 63) >> 6;
    for (int mch = 0; mch < nmch; ++mch) {
      const int segbase = mch << 6;
      int Mv = M - segbase; if (Mv > 64) Mv = 64;
      // per-lane A base address (row = one of this wave's 32 m, cols = its K-half)
      const int m_l = mh * 32 + l31;
      const int sg = segbase + ((m_l < Mv) ? m_l : 0);
      const char* abase;
      if (kh == 0) {
        if (l == 0) {
          int rw = srow[sg], st = sstart[sg];
          abase = wsb + OFF_XBF + ((size_t)((rw * SB + st + r)) * DB + lhi * 8) * 2;
        } else {
          abase = wsb + OFF_H + ((size_t)((((l - 1) * NPAR + (r & 3)) * NSEG_CAP) + sg) * EB + lhi * 8) * 2;
        }
      } else {
        abase = wsb + OFF_H + ((size_t)(((l * NPAR + ((r - 1) & 3)) * NSEG_CAP) + sg) * EB + lhi * 8) * 2;
      }
      f32x16 acc0 = {0.f}, acc1 = {0.f};
      #pragma unroll
      for (int i = 0; i < 16; ++i) { acc0[i] = 0.f; acc1[i] = 0.f; }
      // first 16 k-steps (for l=0/kh=0 this is the whole x half: k<256)
      #pragma unroll
      for (int t = 0; t < 16; t += 2) {
        bf16x8 a0 = *(const bf16x8*)(abase + t * 32);
        acc0 = __builtin_amdgcn_mfma_f32_32x32x16_bf16(a0, breg[t], acc0, 0, 0, 0);
        bf16x8 a1 = *(const bf16x8*)(abase + (t + 1) * 32);
        acc1 = __builtin_amdgcn_mfma_f32_32x32x16_bf16(a1, breg[t + 1], acc1, 0, 0, 0);
      }
      if (!l0k0) {
        #pragma unroll
        for (int t = 16; t < 32; t += 2) {
          bf16x8 a0 = *(const bf16x8*)(abase + t * 32);
          acc0 = __builtin_amdgcn_mfma_f32_32x32x16_bf16(a0, breg[t], acc0, 0, 0, 0);
          bf16x8 a1 = *(const bf16x8*)(abase + (t + 1) * 32);
          acc1 = __builtin_amdgcn_mfma_f32_32x32x16_bf16(a1, breg[t + 1], acc1, 0, 0, 0);
        }
      }
      // ---- K-half partial exchange: D row m=(reg&3)+8*(reg>>2)+4*lhi, col rho=rg*32+l31 ----
      #pragma unroll
      for (int reg = 0; reg < 16; ++reg) {
        int mm = mh * 32 + (reg & 3) + 8 * (reg >> 2) + 4 * lhi;
        glds[kh][mm][rg * 32 + l31] = acc0[reg] + acc1[reg];
      }
      __syncthreads();
      // ---- epilogue: 64 m x 16 e cells over 512 threads ----
      #pragma unroll
      for (int q = 0; q < 2; ++q) {
        int cell = tid + (q << 9);
        int e = cell & 15, m = cell >> 4;
        if (m < Mv) {
          int sg2 = segbase + m;
          float gi = glds[0][m][e]      + glds[1][m][e]      + bias_s[e];
          float gf = glds[0][m][16 + e] + glds[1][m][16 + e] + bias_s[16 + e];
          float gg = glds[0][m][32 + e] + glds[1][m][32 + e] + bias_s[32 + e];
          float go = glds[0][m][48 + e] + glds[1][m][48 + e] + bias_s[48 + e];
          float* cptr = (float*)(ws + OFF_C + ((size_t)(l * NSEG_CAP + sg2) * EB + e0 + e) * 4);
          float cold = *cptr;
          float cnew = sigf(gf) * cold + sigf(gi) * tanhx(gg);
          float hnew = sigf(go) * tanhx(cnew);
          *cptr = cnew;
          *(unsigned short*)(ws + OFF_H +
              ((size_t)(((l * NPAR + (r & 3)) * NSEG_CAP) + sg2) * EB + e0 + e) * 2) = f2bf(hnew);
          if (l == 3) {
            if (r == slen[sg2] - 1) {
              int rw = srow[sg2], sl = sslot[sg2];
              if (sl < Sp) dout[(((long long)rw * Sp + sl) << 9) + e0 + e] = hnew;
            }
          }
        }
      }
      __syncthreads();
    }
    // ---- arrive: one release store, no RMW ----
    if (tid == 0) {
      __threadfence();
      __hip_atomic_store(flags + (((l * 2048 + r) << 5) + wb), 1u,
                         __ATOMIC_RELEASE, __HIP_MEMORY_SCOPE_AGENT);
    }
  }
}

extern "C" void kernel_launch(void* const* d_in, const int* in_sizes, int n_in,
                              void* d_out, int out_size, void* d_ws, size_t ws_size,
                              hipStream_t stream) {
  const float* x    = (const float*)d_in[0];
  const void*  mask = d_in[1];
  const float* wih0 = (const float*)d_in[2];
  const float* wihr = (const float*)d_in[3];
  const float* whh  = (const float*)d_in[4];
  const float* bih  = (const float*)d_in[5];
  const float* bhh  = (const float*)d_in[6];
  float* out = (float*)d_out;
  char* ws = (char*)d_ws;
  int Sp = out_size / (NB * (EB + 1));   // out = N*Sp*E  +  N*Sp mask

  k_conv<<<dim3(2048), dim3(256), 0, stream>>>(x, wih0, wihr, whh, bih, bhh, out, out_size, ws);
  k_seg<<<dim3(1), dim3(256), 0, stream>>>(mask, ws, out, Sp);
  k_main<<<dim3(GRID_MAIN), dim3(512), 0, stream>>>(ws, out, Sp);
}

// Round 5
// 7416.847 us; speedup vs baseline: 2.9449x; 1.0166x over previous
//
#include <hip/hip_runtime.h>
#include <hip/hip_bf16.h>

#define NB 16
#define SB 2048
#define DB 256
#define EB 512
#define LB 4
#define NPAR 4
#define NSEG_CAP 1024
#define GRID_MAIN 128

typedef __bf16 bf16x8 __attribute__((ext_vector_type(8)));
typedef float  f32x4  __attribute__((ext_vector_type(4)));
typedef float  f32x16 __attribute__((ext_vector_type(16)));

// ---------------- workspace layout (bytes) ----------------
#define OFF_XBF   0ull
#define SZ_XBF    (16ull*2048*256*2)          // x as bf16
#define OFF_W     (OFF_XBF + SZ_XBF)          // uniform [l][2048][1024] bf16
#define SZ_W      (4ull*2048*1024*2)
#define OFF_BIAS  (OFF_W + SZ_W)              // 4*2048 f32 (b_ih+b_hh)
#define OFF_H     (OFF_BIAS + 4ull*2048*4)    // [l][par(4)][seg][e] bf16
#define SZ_H      (4ull*NPAR*NSEG_CAP*EB*2)
#define OFF_C     (OFF_H + SZ_H)              // [l][seg][e] f32
#define SZ_C      (4ull*NSEG_CAP*EB*4)
#define OFF_SROW   (OFF_C + SZ_C)
#define OFF_SSTART (OFF_SROW  + 4ull*NSEG_CAP)
#define OFF_SLEN   (OFF_SSTART + 4ull*NSEG_CAP)
#define OFF_SSLOT  (OFF_SLEN  + 4ull*NSEG_CAP)
#define OFF_ACT   (OFF_SSLOT + 4ull*NSEG_CAP) // active[r], 2048 ints
#define OFF_META  (OFF_ACT + 4ull*2048)       // [0]=NSEG [1]=maxlen
#define OFF_FLAGS (OFF_META + 256ull)         // [l][r][32] u32
#define SZ_FLAGS  (4ull*2048*32*4)

__device__ __forceinline__ unsigned short f2bf(float f) {
  union { float f; unsigned u; } v; v.f = f;
  unsigned r = v.u + 0x7FFFu + ((v.u >> 16) & 1u);
  return (unsigned short)(r >> 16);
}
__device__ __forceinline__ float sigf(float x) {
  x = fminf(30.f, fmaxf(-30.f, x));
  return 1.f / (1.f + __expf(-x));
}
__device__ __forceinline__ float tanhx(float x) {
  x = fminf(15.f, fmaxf(-15.f, x));
  float e = __expf(-2.f * x);
  return (1.f - e) / (1.f + e);
}

// ---------------- kernel 1: conversions + zeroing ----------------
__global__ void k_conv(const float* __restrict__ x, const float* __restrict__ wih0,
                       const float* __restrict__ wihr, const float* __restrict__ whh,
                       const float* __restrict__ bih, const float* __restrict__ bhh,
                       float* __restrict__ dout, int out_size, char* __restrict__ ws) {
  long long gid = (long long)blockIdx.x * blockDim.x + threadIdx.x;
  long long stride = (long long)gridDim.x * blockDim.x;
  for (long long i = gid; i < out_size; i += stride) dout[i] = 0.f;
  unsigned* hz = (unsigned*)(ws + OFF_H);
  long long hcw = (long long)(SZ_H + SZ_C) / 4;
  for (long long i = gid; i < hcw; i += stride) hz[i] = 0u;
  unsigned* fz = (unsigned*)(ws + OFF_FLAGS);
  for (long long i = gid; i < (long long)(SZ_FLAGS / 4); i += stride) fz[i] = 0u;
  float* bias = (float*)(ws + OFF_BIAS);
  for (long long i = gid; i < 4 * 2048; i += stride) bias[i] = bih[i] + bhh[i];
  // uniform weights [l][2048 n][1024 k] bf16; l==0: k<256 = W_ih0, 256..511 = 0, 512+ = W_hh[0]
  unsigned short* wbf = (unsigned short*)(ws + OFF_W);
  for (long long i = gid; i < 4ll * 2048 * 1024; i += stride) {
    int l = (int)(i >> 21);
    int rem = (int)(i & ((1 << 21) - 1));
    int n = rem >> 10, k = rem & 1023;
    float v;
    if (l == 0)
      v = (k < 256) ? wih0[n * 256 + k]
        : (k < 512) ? 0.f
        : whh[(long long)n * 512 + (k - 512)];
    else
      v = (k < 512) ? wihr[((long long)(l - 1) * 2048 + n) * 512 + k]
                    : whh[((long long)l * 2048 + n) * 512 + (k - 512)];
    wbf[i] = f2bf(v);
  }
  unsigned short* xb = (unsigned short*)(ws + OFF_XBF);
  for (long long i = gid; i < (long long)NB * SB * DB; i += stride) xb[i] = f2bf(x[i]);
}

// ---------------- kernel 2: segmentation + sort (1 block) ----------------
__global__ void k_seg(const void* __restrict__ maskp, char* __restrict__ ws,
                      float* __restrict__ dout, int Sp) {
  __shared__ unsigned bits[NB][64];
  __shared__ int hist[2050];
  __shared__ int sufx[2051];
  __shared__ int part[256];
  __shared__ unsigned metapk[NSEG_CAP];
  __shared__ int slotar[NSEG_CAP];
  __shared__ int rowcnt[NB];
  __shared__ int flagbits, nseg, maxlen;
  int tid = threadIdx.x;
  if (tid == 0) { flagbits = 0; nseg = 0; maxlen = 0; }
  for (int i = tid; i < 2050; i += 256) hist[i] = 0;
  __syncthreads();
  const unsigned* mw = (const unsigned*)maskp;
  int fb = 0;
  for (int i = tid; i < 8192; i += 256) {
    unsigned w = mw[i];
    if (w == 0x3F800000u) fb |= 2;
    if (w == 0x3FF00000u) fb |= 4;
    if (w & 0xFFFFFF00u) fb |= 1;
    if ((i & 1) && w) fb |= 8;
  }
  if (fb) atomicOr(&flagbits, fb);
  __syncthreads();
  int f = flagbits;
  int kind = (f & 4) ? 3 : (f & 2) ? 2 : (f & 1) ? 0 : (f & 8) ? 1 : 3;
  for (int w = tid; w < NB * 64; w += 256) {
    int row = w >> 6, j = w & 63;
    unsigned b = 0;
    int t0 = j * 32;
    for (int z = 0; z < 32; ++z) {
      long long idx = (long long)row * SB + t0 + z;
      bool sep;
      if (kind == 0)      sep = ((const unsigned char*)maskp)[idx] != 0;
      else if (kind == 1) sep = ((const int*)maskp)[idx] != 0;
      else if (kind == 2) sep = ((const float*)maskp)[idx] != 0.f;
      else                sep = ((const unsigned long long*)maskp)[idx] != 0ull;
      b |= (sep ? 1u : 0u) << z;
    }
    bits[row][j] = b;
  }
  __syncthreads();
  if (tid < NB) {
    int row = tid, i = 0, cnt = 0;
    for (int w = 0; w < 64; ++w) {
      unsigned b = bits[row][w];
      while (b) {
        int z = __ffs(b) - 1; b &= b - 1;
        int t = w * 32 + z;
        if (i != t) {
          int len = t - i;
          int idx = atomicAdd(&nseg, 1);
          if (idx < NSEG_CAP) { metapk[idx] = ((unsigned)row << 23) | ((unsigned)i << 12) | (unsigned)len; slotar[idx] = cnt; }
          atomicAdd(&hist[len], 1); atomicMax(&maxlen, len);
          cnt++;
        }
        i = t + 1;
      }
    }
    if (i != SB) {
      int len = SB - i;
      int idx = atomicAdd(&nseg, 1);
      if (idx < NSEG_CAP) { metapk[idx] = ((unsigned)row << 23) | ((unsigned)i << 12) | (unsigned)len; slotar[idx] = cnt; }
      atomicAdd(&hist[len], 1); atomicMax(&maxlen, len);
      cnt++;
    }
    rowcnt[row] = cnt;
  }
  __syncthreads();
  {
    int lo = tid * 9, hi = lo + 9; if (hi > 2050) hi = 2050;
    int s = 0;
    for (int k = lo; k < hi; ++k) s += hist[k];
    part[tid] = s;
  }
  __syncthreads();
  {
    int tail = 0;
    for (int t2 = tid + 1; t2 < 256; ++t2) tail += part[t2];
    int lo = tid * 9, hi = lo + 9; if (hi > 2050) hi = 2050;
    int run = tail;
    for (int k = hi - 1; k >= lo; --k) { run += hist[k]; sufx[k] = run; }
  }
  __syncthreads();
  int* act = (int*)(ws + OFF_ACT);
  for (int r = tid; r < 2048; r += 256) act[r] = sufx[r + 1];
  for (int i = tid; i < 2050; i += 256) hist[i] = 0;
  __syncthreads();
  int NSEG = nseg < NSEG_CAP ? nseg : NSEG_CAP;
  int* srow = (int*)(ws + OFF_SROW);
  int* sstart = (int*)(ws + OFF_SSTART);
  int* slen = (int*)(ws + OFF_SLEN);
  int* sslot = (int*)(ws + OFF_SSLOT);
  for (int i = tid; i < NSEG; i += 256) {
    unsigned m = metapk[i];
    int len = m & 0xFFF, st = (m >> 12) & 0x7FF, row = (int)(m >> 23);
    int pos = sufx[len + 1] + atomicAdd(&hist[len], 1);
    srow[pos] = row; sstart[pos] = st; slen[pos] = len; sslot[pos] = slotar[i];
  }
  int* meta = (int*)(ws + OFF_META);
  if (tid == 0) { meta[0] = NSEG; meta[1] = maxlen; }
  __syncthreads();
  float* omask = dout + (long long)NB * Sp * EB;
  for (int i = tid; i < NB * Sp; i += 256) {
    int row = i / Sp, slot = i % Sp;
    omask[i] = (slot < rowcnt[row]) ? 0.f : 1.f;
  }
}

// ---- A-load ring machinery (plain cached loads; counted vmcnt; rule #18) ----
#define SI(OFFLIT, SLOT) \
  asm volatile("global_load_dwordx4 %0, %1, off offset:" OFFLIT \
               : "=v"(ar[SLOT]) : "v"(ap))
#define SW(NLIT) \
  asm volatile("s_waitcnt vmcnt(" NLIT ")" ::: "memory"); \
  __builtin_amdgcn_sched_barrier(0)
#define MSTEP(T, SLOT) \
  acc = __builtin_amdgcn_mfma_f32_32x32x16_bf16(ar[SLOT], breg[T], acc, 0, 0, 0)
#define STEPI(T, SLOT, OFFLIT) SW("11"); MSTEP(T, SLOT); SI(OFFLIT, SLOT)
#define STEPN(T, SLOT, NLIT)   SW(NLIT); MSTEP(T, SLOT)

// ---------------- kernel 3: persistent dataflow LSTM pipeline ----------------
// block = (layer l, 16 e-values) -> 64 W-rows. 8 waves = (rg: row-half, kh: K-half, mh: m-half).
// B (weights) register-stationary and PINNED: 32 frags x 4 VGPR = 128 VGPR per wave.
__global__ void __launch_bounds__(512, 1)
k_main(char* __restrict__ ws, float* __restrict__ dout, int Sp) {
  __shared__ float glds[2][64][65];   // [kh][m][rho] partial-gate exchange
  __shared__ float bias_s[64];
  __shared__ int act_s[2048];
  const int tid = threadIdx.x;
  const int l = blockIdx.x >> 5, wb = blockIdx.x & 31, e0 = wb << 4;
  const int wave = tid >> 6, lane = tid & 63;
  const int mh = wave & 1, kh = (wave >> 1) & 1, rg = wave >> 2;
  const int l31 = lane & 31, lhi = lane >> 5;

  {
    const int* act = (const int*)(ws + OFF_ACT);
    for (int i = tid; i < 2048; i += 512) act_s[i] = act[i];
    if (tid < 64) bias_s[tid] =
        ((const float*)(ws + OFF_BIAS))[l * 2048 + (tid >> 4) * 512 + e0 + (tid & 15)];
  }
  const int maxlen = ((const int*)(ws + OFF_META))[1];
  const char* wsb = ws;

  // ---- load B-frags (this wave's 32 rows x its K-half) into registers ----
  bf16x8 breg[32];
  {
    int rho = rg * 32 + l31;                 // local row 0..63
    int g = rho >> 4, e = rho & 15;
    const char* wrow = wsb + OFF_W + ((size_t)(l * 2048 + g * 512 + e0 + e)) * 2048;
    const int kbase = kh * 512 + lhi * 8;
    #pragma unroll
    for (int t = 0; t < 32; ++t)
      breg[t] = *(const bf16x8*)(wrow + (size_t)(kbase + t * 16) * 2);
  }
  __syncthreads();

  const int* srow  = (const int*)(ws + OFF_SROW);
  const int* sstart = (const int*)(ws + OFF_SSTART);
  const int* slen  = (const int*)(ws + OFF_SLEN);
  const int* sslot = (const int*)(ws + OFF_SSLOT);
  unsigned* flags = (unsigned*)(ws + OFF_FLAGS);

  for (int r = 0; r < maxlen; ++r) {
    // ---- pin breg live in VGPRs across the whole loop (forbid remat) ----
    #pragma unroll
    for (int t = 0; t < 32; ++t) asm volatile("" : "+v"(breg[t]));
    // ---- dataflow wait: producer (l-1,r), recurrence (l,r-1), back-pressure (l+1,r-4) ----
    const bool nA = (l > 0), nB = (r > 0), nC = (l < 3) && (r >= 4);
    if (wave == 0 && (nA | nB | nC)) {
      int li = lane & 31;
      while (true) {
        unsigned ok = 1;
        if (nA) ok &= (__hip_atomic_load(flags + ((((l - 1) * 2048 + r) << 5) + li),
                                         __ATOMIC_RELAXED, __HIP_MEMORY_SCOPE_AGENT) != 0);
        if (nB) ok &= (__hip_atomic_load(flags + (((l * 2048 + (r - 1)) << 5) + li),
                                         __ATOMIC_RELAXED, __HIP_MEMORY_SCOPE_AGENT) != 0);
        if (nC) ok &= (__hip_atomic_load(flags + ((((l + 1) * 2048 + (r - 4)) << 5) + li),
                                         __ATOMIC_RELAXED, __HIP_MEMORY_SCOPE_AGENT) != 0);
        if (__all((int)ok)) break;
        __builtin_amdgcn_s_sleep(2);
      }
      __threadfence();   // acquire
    }
    __syncthreads();

    const int M = act_s[r];
    const int nmch = (M + 63) >> 6;
    for (int mch = 0; mch < nmch; ++mch) {
      const int segbase = mch << 6;
      int Mv = M - segbase; if (Mv > 64) Mv = 64;
      const int m_l = mh * 32 + l31;
      const int sg = segbase + ((m_l < Mv) ? m_l : 0);
      const char* ap;
      if (kh == 0) {
        if (l == 0) {
          int rw = srow[sg], st = sstart[sg];
          ap = wsb + OFF_XBF + ((size_t)((rw * SB + st + r)) * DB + lhi * 8) * 2;
        } else {
          ap = wsb + OFF_H + ((size_t)((((l - 1) * NPAR + (r & 3)) * NSEG_CAP) + sg) * EB + lhi * 8) * 2;
        }
      } else {
        ap = wsb + OFF_H + ((size_t)(((l * NPAR + ((r - 1) & 3)) * NSEG_CAP) + sg) * EB + lhi * 8) * 2;
      }
      // ---- early c-prefetch (block-private; consumed after final drain) ----
      const int em0 = tid >> 4, ee = tid & 15;             // q=0 cell
      float* cp0 = (float*)(ws + OFF_C + ((size_t)(l * NSEG_CAP + segbase + em0) * EB + e0 + ee) * 4);
      float* cp1 = (float*)(ws + OFF_C + ((size_t)(l * NSEG_CAP + segbase + em0 + 32) * EB + e0 + ee) * 4);
      float cold0 = *cp0, cold1 = *cp1;
      f32x16 acc;
      #pragma unroll
      for (int i = 0; i < 16; ++i) acc[i] = 0.f;
      bf16x8 ar[12];
      // prologue: fill 12-deep ring
      SI("0",0);   SI("32",1);  SI("64",2);  SI("96",3);
      SI("128",4); SI("160",5); SI("192",6); SI("224",7);
      SI("256",8); SI("288",9); SI("320",10); SI("352",11);
      // steady state: wait(11) -> MFMA(t) -> issue(t+12)
      STEPI(0,0,"384");  STEPI(1,1,"416");  STEPI(2,2,"448");  STEPI(3,3,"480");
      STEPI(4,4,"512");  STEPI(5,5,"544");  STEPI(6,6,"576");  STEPI(7,7,"608");
      STEPI(8,8,"640");  STEPI(9,9,"672");  STEPI(10,10,"704"); STEPI(11,11,"736");
      STEPI(12,0,"768"); STEPI(13,1,"800"); STEPI(14,2,"832"); STEPI(15,3,"864");
      STEPI(16,4,"896"); STEPI(17,5,"928"); STEPI(18,6,"960"); STEPI(19,7,"992");
      // drain
      STEPN(20,8,"11"); STEPN(21,9,"10"); STEPN(22,10,"9"); STEPN(23,11,"8");
      STEPN(24,0,"7");  STEPN(25,1,"6");  STEPN(26,2,"5");  STEPN(27,3,"4");
      STEPN(28,4,"3");  STEPN(29,5,"2");  STEPN(30,6,"1");  STEPN(31,7,"0");
      // ---- K-half partial exchange: D row m=(reg&3)+8*(reg>>2)+4*lhi, col rho=rg*32+l31 ----
      #pragma unroll
      for (int reg = 0; reg < 16; ++reg) {
        int mm = mh * 32 + (reg & 3) + 8 * (reg >> 2) + 4 * lhi;
        glds[kh][mm][rg * 32 + l31] = acc[reg];
      }
      __syncthreads();
      // ---- epilogue: 64 m x 16 e cells over 512 threads (2 cells/thread) ----
      #pragma unroll
      for (int q = 0; q < 2; ++q) {
        int m = em0 + q * 32, e = ee;
        float cold = q ? cold1 : cold0;
        float* cptr = q ? cp1 : cp0;
        if (m < Mv) {
          int sg2 = segbase + m;
          float gi = glds[0][m][e]      + glds[1][m][e]      + bias_s[e];
          float gf = glds[0][m][16 + e] + glds[1][m][16 + e] + bias_s[16 + e];
          float gg = glds[0][m][32 + e] + glds[1][m][32 + e] + bias_s[32 + e];
          float go = glds[0][m][48 + e] + glds[1][m][48 + e] + bias_s[48 + e];
          float cnew = sigf(gf) * cold + sigf(gi) * tanhx(gg);
          float hnew = sigf(go) * tanhx(cnew);
          *cptr = cnew;
          *(unsigned short*)(ws + OFF_H +
              ((size_t)(((l * NPAR + (r & 3)) * NSEG_CAP) + sg2) * EB + e0 + e) * 2) = f2bf(hnew);
          if (l == 3) {
            if (r == slen[sg2] - 1) {
              int rw = srow[sg2], sl = sslot[sg2];
              if (sl < Sp) dout[(((long long)rw * Sp + sl) << 9) + e0 + e] = hnew;
            }
          }
        }
      }
      __syncthreads();
    }
    // ---- release: barrier already drained stores; flush L2, set flag ----
    if (tid == 0) {
      __threadfence();
      __hip_atomic_store(flags + (((l * 2048 + r) << 5) + wb), 1u,
                         __ATOMIC_RELEASE, __HIP_MEMORY_SCOPE_AGENT);
    }
  }
}

extern "C" void kernel_launch(void* const* d_in, const int* in_sizes, int n_in,
                              void* d_out, int out_size, void* d_ws, size_t ws_size,
                              hipStream_t stream) {
  const float* x    = (const float*)d_in[0];
  const void*  mask = d_in[1];
  const float* wih0 = (const float*)d_in[2];
  const float* wihr = (const float*)d_in[3];
  const float* whh  = (const float*)d_in[4];
  const float* bih  = (const float*)d_in[5];
  const float* bhh  = (const float*)d_in[6];
  float* out = (float*)d_out;
  char* ws = (char*)d_ws;
  int Sp = out_size / (NB * (EB + 1));   // out = N*Sp*E  +  N*Sp mask

  k_conv<<<dim3(2048), dim3(256), 0, stream>>>(x, wih0, wihr, whh, bih, bhh, out, out_size, ws);
  k_seg<<<dim3(1), dim3(256), 0, stream>>>(mask, ws, out, Sp);
  k_main<<<dim3(GRID_MAIN), dim3(512), 0, stream>>>(ws, out, Sp);
}